// Round 4
// baseline (861.151 us; speedup 1.0000x reference)
//
#include <hip/hip_runtime.h>
#include <hip/hip_bf16.h>

typedef unsigned short u16;
typedef unsigned int   u32;
typedef unsigned long long u64;
typedef __attribute__((ext_vector_type(8))) short bf16x8;  // 8 bf16 = 4 VGPRs
typedef __attribute__((ext_vector_type(4))) float f32x4;

#define BB 4
#define CC 512
#define NN 4096
#define LOG2E 1.44269504f

static __device__ __forceinline__ u16 f2b(float f) {
    __hip_bfloat16 h = __float2bfloat16(f);
    return *(u16*)&h;
}
static __device__ __forceinline__ float b2f(u16 b) {
    u32 u = (u32)b << 16;
    return __builtin_bit_cast(float, u);
}

// async global -> LDS, 16B per lane, wave-uniform LDS base + lane*16
typedef __attribute__((address_space(1))) const u32 GU32;
typedef __attribute__((address_space(3))) u32 LU32;
__device__ __forceinline__ void async16(const void* g, void* l) {
    __builtin_amdgcn_global_load_lds((GU32*)g, (LU32*)l, 16, 0, 0);
}

// ---------------------------------------------------------------------------
// prep: x fp32 [B][C][N] -> XT bf16 [B][N][c-swizzled] (chunk^= n&7),
//       XN bf16 [B][C][N], norms[b][n] = sum_c x^2, maxn[b] = max_n norms
// One block per (b, n0): owns all 512 c -> no global atomics on norms.
// ---------------------------------------------------------------------------
__global__ __launch_bounds__(256) void prep_kernel(const float* __restrict__ x,
                                                   u16* __restrict__ XT,
                                                   u16* __restrict__ XN,
                                                   float* __restrict__ norms,
                                                   int* __restrict__ maxn) {
    __shared__ __align__(8) u16 tile[64][68];
    __shared__ float nsum[64];
    int blk = blockIdx.x;                  // 256 blocks
    int b  = blk >> 6;
    int n0 = (blk & 63) << 6;
    int t  = threadIdx.x;
    if (t < 64) nsum[t] = 0.f;

    int nq    = t & 15;
    int rbase = t >> 4;
    float psum[4] = {0.f, 0.f, 0.f, 0.f};

    for (int c0 = 0; c0 < CC; c0 += 64) {
        #pragma unroll
        for (int p = 0; p < 4; ++p) {
            int cl = p * 16 + rbase;
            const float* src = x + ((size_t)(b * CC + c0 + cl) * NN) + n0 + nq * 4;
            float4 v = *(const float4*)src;
            psum[0] += v.x * v.x; psum[1] += v.y * v.y;
            psum[2] += v.z * v.z; psum[3] += v.w * v.w;
            u64 pk = (u64)f2b(v.x) | ((u64)f2b(v.y) << 16) |
                     ((u64)f2b(v.z) << 32) | ((u64)f2b(v.w) << 48);
            *(u64*)&XN[((size_t)(b * CC + c0 + cl) * NN) + n0 + nq * 4] = pk;
            *(u64*)&tile[cl][nq * 4] = pk;
        }
        __syncthreads();
        int c2 = (t & 31) * 2;             // 0..62 even
        int nb = t >> 5;                   // 0..7
        #pragma unroll
        for (int rr = 0; rr < 8; ++rr) {
            int nl = rr * 8 + nb;
            u32 val = (u32)tile[c2][nl] | ((u32)tile[c2 + 1][nl] << 16);
            int c  = c0 + c2;
            int cs = ((((c >> 3) ^ (nl & 7)) << 3) | (c & 7));   // XOR swizzle
            *(u32*)&XT[((size_t)(b * NN + n0 + nl) * CC) + cs] = val;
        }
        __syncthreads();
    }
    #pragma unroll
    for (int k = 0; k < 4; ++k) atomicAdd(&nsum[nq * 4 + k], psum[k]);
    __syncthreads();
    if (t < 64) {
        float v = nsum[t];
        norms[(size_t)b * NN + n0 + t] = v;
        float m = v;
        #pragma unroll
        for (int d = 1; d < 64; d <<= 1) m = fmaxf(m, __shfl_xor(m, d));
        if (t == 0) atomicMax(&maxn[b], __float_as_int(m));  // norms >= 0
    }
}

// ---------------------------------------------------------------------------
// flash attention, static per-row max bound. 1 barrier/iter, KtT dbuf,
// XOR-swizzled K layout (conflict-free GEMM1 reads), u32 P writes.
// ---------------------------------------------------------------------------
__global__ __launch_bounds__(256, 2) void flash_kernel(const u16* __restrict__ XT,
                                                       const u16* __restrict__ XN,
                                                       const float* __restrict__ norms,
                                                       const int* __restrict__ maxn,
                                                       float* __restrict__ outF,
                                                       u16* __restrict__ outH,
                                                       float* __restrict__ l0g,
                                                       float* __restrict__ l1g,
                                                       int split) {
    __shared__ __align__(16) u16 KtT[2][32 * 512];        // [j][c-swizzled]
    __shared__ __align__(16) u16 Plds[2][64 * 40];        // stride 40
    __shared__ float lLds[64];

    int blk   = blockIdx.x;
    int inner = blk & 255;
    int hf    = split ? (blk >> 8) : 0;
    int xcd = inner & 7;
    int b   = xcd >> 1;
    int ib  = (inner >> 3) + ((xcd & 1) << 5);
    int i_base = ib * 64;
    int jlo = hf * (NN / 2) * split;
    int njt = split ? 64 : 128;

    int t    = threadIdx.x;
    int w    = t >> 6;
    int lane = t & 63;
    int l15  = lane & 15;
    int q    = lane >> 4;

    const u16* xtb = XT + (size_t)b * NN * CC;
    const u16* xnb = XN + (size_t)b * CC * NN;

    float mxn = __int_as_float(maxn[b]);
    float M2[4];
    #pragma unroll
    for (int r = 0; r < 4; ++r) {
        float nr = norms[(size_t)b * NN + i_base + w * 16 + q * 4 + r];
        M2[r] = (sqrtf(nr * mxn) - 40.f) * LOG2E;
    }

    // Q fragments (rows i_base + w*16 + l15); account for XOR swizzle of XT
    int sw = l15 & 7;
    bf16x8 qf[16];
    {
        const u16* qrow = xtb + (size_t)(i_base + w * 16 + l15) * CC;
        #pragma unroll
        for (int kk = 0; kk < 16; ++kk)
            qf[kk] = *(const bf16x8*)(qrow + (((kk * 4 + q) ^ sw) << 3));
    }

    f32x4 o[8][4];
    #pragma unroll
    for (int ct = 0; ct < 8; ++ct)
        #pragma unroll
        for (int it = 0; it < 4; ++it)
            o[ct][it] = (f32x4){0.f, 0.f, 0.f, 0.f};
    float lpart[4] = {0.f, 0.f, 0.f, 0.f};

    // GEMM1 B rows: j = 2*l15 and 2*l15+1 (adjacent P columns)
    int r0  = 2 * l15;
    int sw0 = r0 & 7, sw1 = (r0 + 1) & 7;

    // prologue: stage tile 0
    {
        const u16* src = xtb + (size_t)(jlo + w * 8) * CC + lane * 8;
        #pragma unroll
        for (int rr = 0; rr < 8; ++rr)
            async16(src + rr * CC, &KtT[0][(w * 8 + rr) * 512]);
    }
    __syncthreads();

    for (int jt = 0; jt < njt; ++jt) {
        int buf = jt & 1;
        int j0  = jlo + jt * 32;

        // V fragments for THIS iter (drained at the barrier below)
        bf16x8 vf[8];
        #pragma unroll
        for (int ct = 0; ct < 8; ++ct)
            vf[ct] = *(const bf16x8*)(xnb + (size_t)(w * 128 + ct * 16 + l15) * NN + j0 + q * 8);

        // stage NEXT K-tile into the other buffer
        if (jt + 1 < njt) {
            const u16* src = xtb + (size_t)(j0 + 32 + w * 8) * CC + lane * 8;
            #pragma unroll
            for (int rr = 0; rr < 8; ++rr)
                async16(src + rr * CC, &KtT[buf ^ 1][(w * 8 + rr) * 512]);
        }

        // GEMM1: 4 accumulator chains, conflict-free swizzled reads
        const u16* kb = &KtT[buf][0];
        f32x4 s0a = {0.f,0.f,0.f,0.f}, s1a = {0.f,0.f,0.f,0.f};
        f32x4 s0b = {0.f,0.f,0.f,0.f}, s1b = {0.f,0.f,0.f,0.f};
        #pragma unroll
        for (int kk = 0; kk < 8; ++kk) {
            bf16x8 b0 = *(const bf16x8*)&kb[ r0      * 512 + (((kk * 4 + q) ^ sw0) << 3)];
            bf16x8 b1 = *(const bf16x8*)&kb[(r0 + 1) * 512 + (((kk * 4 + q) ^ sw1) << 3)];
            s0a = __builtin_amdgcn_mfma_f32_16x16x32_bf16(qf[kk], b0, s0a, 0, 0, 0);
            s1a = __builtin_amdgcn_mfma_f32_16x16x32_bf16(qf[kk], b1, s1a, 0, 0, 0);
        }
        #pragma unroll
        for (int kk = 8; kk < 16; ++kk) {
            bf16x8 b0 = *(const bf16x8*)&kb[ r0      * 512 + (((kk * 4 + q) ^ sw0) << 3)];
            bf16x8 b1 = *(const bf16x8*)&kb[(r0 + 1) * 512 + (((kk * 4 + q) ^ sw1) << 3)];
            s0b = __builtin_amdgcn_mfma_f32_16x16x32_bf16(qf[kk], b0, s0b, 0, 0, 0);
            s1b = __builtin_amdgcn_mfma_f32_16x16x32_bf16(qf[kk], b1, s1b, 0, 0, 0);
        }
        f32x4 s0 = s0a + s0b, s1 = s1a + s1b;

        // softmax-lite; P cols (2*l15, 2*l15+1) -> single u32 write
        #pragma unroll
        for (int r = 0; r < 4; ++r) {
            float p0 = __builtin_amdgcn_exp2f(fmaf(s0[r], LOG2E, -M2[r]));
            float p1 = __builtin_amdgcn_exp2f(fmaf(s1[r], LOG2E, -M2[r]));
            lpart[r] += p0 + p1;
            u32 w01 = ((__builtin_bit_cast(u32, p0) + 0x8000u) >> 16) |
                      ((__builtin_bit_cast(u32, p1) + 0x8000u) & 0xffff0000u);
            int row = w * 16 + q * 4 + r;
            *(u32*)&Plds[buf][row * 40 + r0] = w01;
        }
        __syncthreads();   // drains vf + stage(i+1); P ready

        // GEMM2: O^T += V P^T
        bf16x8 pb[4];
        #pragma unroll
        for (int it = 0; it < 4; ++it)
            pb[it] = *(const bf16x8*)&Plds[buf][(it * 16 + l15) * 40 + q * 8];
        #pragma unroll
        for (int ct = 0; ct < 8; ++ct)
            #pragma unroll
            for (int it = 0; it < 4; ++it)
                o[ct][it] = __builtin_amdgcn_mfma_f32_16x16x32_bf16(vf[ct], pb[it], o[ct][it], 0, 0, 0);
    }

    // reduce l over the 16 column-lanes
    #pragma unroll
    for (int r = 0; r < 4; ++r) {
        float s = lpart[r];
        s += __shfl_xor(s, 1);
        s += __shfl_xor(s, 2);
        s += __shfl_xor(s, 4);
        s += __shfl_xor(s, 8);
        lpart[r] = s;
    }

    if (!split) {
        if (l15 == 0) {
            #pragma unroll
            for (int r = 0; r < 4; ++r) lLds[w * 16 + q * 4 + r] = lpart[r];
        }
        __syncthreads();
        float linv[4];
        #pragma unroll
        for (int it = 0; it < 4; ++it) linv[it] = 1.f / lLds[it * 16 + l15];
        float* ob = outF + (size_t)b * CC * NN;
        #pragma unroll
        for (int ct = 0; ct < 8; ++ct)
            #pragma unroll
            for (int r = 0; r < 4; ++r) {
                int c = w * 128 + ct * 16 + q * 4 + r;
                float* orow = ob + (size_t)c * NN + i_base;
                #pragma unroll
                for (int it = 0; it < 4; ++it)
                    orow[it * 16 + l15] = o[ct][it][r] * linv[it];
            }
    } else {
        if (l15 == 0) {
            float* lg = (hf == 0) ? l0g : l1g;
            #pragma unroll
            for (int r = 0; r < 4; ++r)
                lg[(size_t)b * NN + i_base + w * 16 + q * 4 + r] = lpart[r];
        }
        if (hf == 0) {
            float* ob = outF + (size_t)b * CC * NN;
            #pragma unroll
            for (int ct = 0; ct < 8; ++ct)
                #pragma unroll
                for (int r = 0; r < 4; ++r) {
                    int c = w * 128 + ct * 16 + q * 4 + r;
                    float* orow = ob + (size_t)c * NN + i_base;
                    #pragma unroll
                    for (int it = 0; it < 4; ++it)
                        orow[it * 16 + l15] = o[ct][it][r];       // unnormalized
                }
        } else {
            u16* ob = outH + (size_t)b * CC * NN;
            #pragma unroll
            for (int ct = 0; ct < 8; ++ct)
                #pragma unroll
                for (int r = 0; r < 4; ++r) {
                    int c = w * 128 + ct * 16 + q * 4 + r;
                    u16* orow = ob + (size_t)c * NN + i_base;
                    #pragma unroll
                    for (int it = 0; it < 4; ++it)
                        orow[it * 16 + l15] = f2b(o[ct][it][r]);
                }
        }
    }
}

// combine: out = (O0 + O1) / (l0 + l1)
__global__ __launch_bounds__(256) void combine_kernel(float* __restrict__ out,
                                                      const u16* __restrict__ P1,
                                                      const float* __restrict__ l0,
                                                      const float* __restrict__ l1) {
    size_t g = (size_t)blockIdx.x * 256 + threadIdx.x;
    size_t f = g * 4;
    int i = (int)(f & (NN - 1));
    int b = (int)(f >> 21);
    float4 p0 = *(float4*)&out[f];
    u64 pk = *(const u64*)&P1[f];
    float p0a[4] = {p0.x, p0.y, p0.z, p0.w};
    float r[4];
    #pragma unroll
    for (int k = 0; k < 4; ++k) {
        float l = l0[(size_t)b * NN + i + k] + l1[(size_t)b * NN + i + k];
        float p1f = b2f((u16)((pk >> (16 * k)) & 0xFFFFu));
        r[k] = (p0a[k] + p1f) / l;
    }
    *(float4*)&out[f] = (float4){r[0], r[1], r[2], r[3]};
}

extern "C" void kernel_launch(void* const* d_in, const int* in_sizes, int n_in,
                              void* d_out, int out_size, void* d_ws, size_t ws_size,
                              hipStream_t stream) {
    const float* x = (const float*)d_in[0];
    size_t SZ = (size_t)BB * NN * CC;          // elements
    u16* XT = (u16*)d_ws;
    u16* XN = XT + SZ;
    u16* P1 = XN + SZ;
    float* norms = (float*)(P1 + SZ);
    float* l0g   = norms + (size_t)BB * NN;
    float* l1g   = l0g + (size_t)BB * NN;
    int*   maxn  = (int*)(l1g + (size_t)BB * NN);
    size_t needed = 3 * SZ * 2 + 3 * (size_t)BB * NN * 4 + 64;
    int split = (ws_size >= needed) ? 1 : 0;
    float* out = (float*)d_out;
    if (!split) {
        norms = (float*)(XN + SZ);
        l0g = norms + (size_t)BB * NN;
        l1g = l0g;
        maxn = (int*)(l1g + (size_t)BB * NN);
    }

    hipMemsetAsync(maxn, 0, BB * sizeof(int), stream);
    prep_kernel<<<256, 256, 0, stream>>>(x, XT, XN, norms, maxn);
    if (split) {
        flash_kernel<<<512, 256, 0, stream>>>(XT, XN, norms, maxn, out, P1, l0g, l1g, 1);
        combine_kernel<<<(BB * CC * NN / 4) / 256, 256, 0, stream>>>(out, P1, l0g, l1g);
    } else {
        flash_kernel<<<256, 256, 0, stream>>>(XT, XN, norms, maxn, out, P1, l0g, l1g, 0);
    }
}

// Round 5
// 363.403 us; speedup vs baseline: 2.3697x; 2.3697x over previous
//
#include <hip/hip_runtime.h>
#include <hip/hip_bf16.h>

typedef unsigned short u16;
typedef unsigned int   u32;
typedef unsigned long long u64;
typedef __attribute__((ext_vector_type(8))) short bf16x8;  // 8 bf16 = 4 VGPRs
typedef __attribute__((ext_vector_type(4))) float f32x4;

#define BB 4
#define CC 512
#define NN 4096
#define LOG2E 1.44269504f

static __device__ __forceinline__ u16 f2b(float f) {
    __hip_bfloat16 h = __float2bfloat16(f);
    return *(u16*)&h;
}
static __device__ __forceinline__ u16 f2b_fast(float f) {   // round-half-up bf16
    u32 u = __builtin_bit_cast(u32, f);
    return (u16)((u + 0x8000u) >> 16);
}
static __device__ __forceinline__ float b2f(u16 b) {
    u32 u = (u32)b << 16;
    return __builtin_bit_cast(float, u);
}

// async global -> LDS, 16B per lane, wave-uniform LDS base + lane*16
typedef __attribute__((address_space(1))) const u32 GU32;
typedef __attribute__((address_space(3))) u32 LU32;
__device__ __forceinline__ void async16(const void* g, void* l) {
    __builtin_amdgcn_global_load_lds((GU32*)g, (LU32*)l, 16, 0, 0);
}

// ---------------------------------------------------------------------------
// prep: x fp32 [B][C][N] -> XT bf16 [B][N][C] (plain layout), XN bf16 [B][C][N],
//       norms[b][n] = sum_c x^2, maxn[b] = max_n norms (exact: block owns all c)
// ---------------------------------------------------------------------------
__global__ __launch_bounds__(256) void prep_kernel(const float* __restrict__ x,
                                                   u16* __restrict__ XT,
                                                   u16* __restrict__ XN,
                                                   float* __restrict__ norms,
                                                   int* __restrict__ maxn) {
    __shared__ __align__(8) u16 tile[64][68];
    __shared__ float nsum[64];
    int blk = blockIdx.x;                  // 256 blocks
    int b  = blk >> 6;
    int n0 = (blk & 63) << 6;
    int t  = threadIdx.x;
    if (t < 64) nsum[t] = 0.f;

    int nq    = t & 15;
    int rbase = t >> 4;
    float psum[4] = {0.f, 0.f, 0.f, 0.f};

    for (int c0 = 0; c0 < CC; c0 += 64) {
        #pragma unroll
        for (int p = 0; p < 4; ++p) {
            int cl = p * 16 + rbase;
            const float* src = x + ((size_t)(b * CC + c0 + cl) * NN) + n0 + nq * 4;
            float4 v = *(const float4*)src;
            psum[0] += v.x * v.x; psum[1] += v.y * v.y;
            psum[2] += v.z * v.z; psum[3] += v.w * v.w;
            u64 pk = (u64)f2b(v.x) | ((u64)f2b(v.y) << 16) |
                     ((u64)f2b(v.z) << 32) | ((u64)f2b(v.w) << 48);
            *(u64*)&XN[((size_t)(b * CC + c0 + cl) * NN) + n0 + nq * 4] = pk;
            *(u64*)&tile[cl][nq * 4] = pk;
        }
        __syncthreads();
        int c2 = (t & 31) * 2;             // 0..62 even
        int nb = t >> 5;                   // 0..7
        #pragma unroll
        for (int rr = 0; rr < 8; ++rr) {
            int nl = rr * 8 + nb;
            u32 val = (u32)tile[c2][nl] | ((u32)tile[c2 + 1][nl] << 16);
            *(u32*)&XT[((size_t)(b * NN + n0 + nl) * CC) + c0 + c2] = val;
        }
        __syncthreads();
    }
    #pragma unroll
    for (int k = 0; k < 4; ++k) atomicAdd(&nsum[nq * 4 + k], psum[k]);
    __syncthreads();
    if (t < 64) {
        float v = nsum[t];
        norms[(size_t)b * NN + n0 + t] = v;
        float m = v;
        #pragma unroll
        for (int d = 1; d < 64; d <<= 1) m = fmaxf(m, __shfl_xor(m, d));
        if (t == 0) atomicMax(&maxn[b], __float_as_int(m));  // norms >= 0
    }
}

// ---------------------------------------------------------------------------
// flash attention, static per-row max bound (no online rescale, no shuffles
// in the loop). 1 barrier/iter, KtT double-buffered, async staging.
// Register budget is EXACTLY at the 256/wave cliff (o=128 AGPR + qf 64 +
// vf 32 + s 8 + addr) — do not add live state in the loop (R4 spilled).
// ---------------------------------------------------------------------------
__global__ __launch_bounds__(256, 2) void flash_kernel(const u16* __restrict__ XT,
                                                       const u16* __restrict__ XN,
                                                       const float* __restrict__ norms,
                                                       const int* __restrict__ maxn,
                                                       float* __restrict__ outF,
                                                       u16* __restrict__ outH,
                                                       float* __restrict__ l0g,
                                                       float* __restrict__ l1g,
                                                       int split) {
    __shared__ __align__(16) u16 KtT[2][32 * 520];        // [j][c], stride 520
    __shared__ __align__(16) u16 Plds[2][64 * 40];
    __shared__ float lLds[64];

    int blk   = blockIdx.x;
    int inner = blk & 255;
    int hf    = split ? (blk >> 8) : 0;
    int xcd = inner & 7;
    int b   = xcd >> 1;
    int ib  = (inner >> 3) + ((xcd & 1) << 5);
    int i_base = ib * 64;
    int jlo = hf * (NN / 2) * split;
    int njt = split ? 64 : 128;

    int t    = threadIdx.x;
    int w    = t >> 6;
    int lane = t & 63;
    int l15  = lane & 15;
    int q    = lane >> 4;

    const u16* xtb = XT + (size_t)b * NN * CC;
    const u16* xnb = XN + (size_t)b * CC * NN;

    float mxn = __int_as_float(maxn[b]);
    float M2[4];
    #pragma unroll
    for (int r = 0; r < 4; ++r) {
        float nr = norms[(size_t)b * NN + i_base + w * 16 + q * 4 + r];
        M2[r] = (sqrtf(nr * mxn) - 40.f) * LOG2E;
    }

    // Q fragments: rows i_base + w*16 + l15, all 512 c
    bf16x8 qf[16];
    {
        const u16* qrow = xtb + (size_t)(i_base + w * 16 + l15) * CC;
        #pragma unroll
        for (int kk = 0; kk < 16; ++kk)
            qf[kk] = *(const bf16x8*)(qrow + kk * 32 + q * 8);
    }

    f32x4 o[8][4];
    #pragma unroll
    for (int ct = 0; ct < 8; ++ct)
        #pragma unroll
        for (int it = 0; it < 4; ++it)
            o[ct][it] = (f32x4){0.f, 0.f, 0.f, 0.f};
    float lpart[4] = {0.f, 0.f, 0.f, 0.f};

    // loop-invariant pointers (advance by constants each iter)
    const u16* vfp = xnb + (size_t)(w * 128 + l15) * NN + jlo + q * 8;  // vf base
    const u16* stp = xtb + (size_t)(jlo + 32 + w * 8) * CC + lane * 8;  // next-tile staging

    // prologue: stage tile 0
    {
        const u16* src = xtb + (size_t)(jlo + w * 8) * CC + lane * 8;
        #pragma unroll
        for (int rr = 0; rr < 8; ++rr)
            async16(src + rr * CC, &KtT[0][(w * 8 + rr) * 520]);
    }
    __syncthreads();

    for (int jt = 0; jt < njt; ++jt) {
        int buf = jt & 1;

        // V fragments for THIS iter (drained at the barrier below)
        bf16x8 vf[8];
        #pragma unroll
        for (int ct = 0; ct < 8; ++ct)
            vf[ct] = *(const bf16x8*)(vfp + (size_t)ct * 16 * NN);
        vfp += 32;

        // stage NEXT K-tile into the other buffer
        if (jt + 1 < njt) {
            #pragma unroll
            for (int rr = 0; rr < 8; ++rr)
                async16(stp + rr * CC, &KtT[buf ^ 1][(w * 8 + rr) * 520]);
        }
        stp += 32 * CC;

        // GEMM1: S[16 rows][32 j] from KtT[buf]  (2 chains — do not widen)
        f32x4 s0 = {0.f,0.f,0.f,0.f}, s1 = {0.f,0.f,0.f,0.f};
        #pragma unroll
        for (int kk = 0; kk < 16; ++kk) {
            bf16x8 b0 = *(const bf16x8*)&KtT[buf][(l15)      * 520 + kk * 32 + q * 8];
            bf16x8 b1 = *(const bf16x8*)&KtT[buf][(16 + l15) * 520 + kk * 32 + q * 8];
            s0 = __builtin_amdgcn_mfma_f32_16x16x32_bf16(qf[kk], b0, s0, 0, 0, 0);
            s1 = __builtin_amdgcn_mfma_f32_16x16x32_bf16(qf[kk], b1, s1, 0, 0, 0);
        }

        // softmax-lite: p = 2^(s*log2e - M2); no shuffles, no rescale
        #pragma unroll
        for (int r = 0; r < 4; ++r) {
            float p0 = __builtin_amdgcn_exp2f(fmaf(s0[r], LOG2E, -M2[r]));
            float p1 = __builtin_amdgcn_exp2f(fmaf(s1[r], LOG2E, -M2[r]));
            u16 h0 = f2b_fast(p0), h1 = f2b_fast(p1);
            lpart[r] += b2f(h0) + b2f(h1);       // l consistent with bf16 P
            int row = w * 16 + q * 4 + r;
            Plds[buf][row * 40 +      l15] = h0;
            Plds[buf][row * 40 + 16 + l15] = h1;
        }
        __syncthreads();   // drains vf + stage(i+1); P ready

        // GEMM2: O^T += V P^T
        bf16x8 pb[4];
        #pragma unroll
        for (int it = 0; it < 4; ++it)
            pb[it] = *(const bf16x8*)&Plds[buf][(it * 16 + l15) * 40 + q * 8];
        #pragma unroll
        for (int ct = 0; ct < 8; ++ct)
            #pragma unroll
            for (int it = 0; it < 4; ++it)
                o[ct][it] = __builtin_amdgcn_mfma_f32_16x16x32_bf16(vf[ct], pb[it], o[ct][it], 0, 0, 0);
    }

    // reduce l over the 16 column-lanes (once)
    #pragma unroll
    for (int r = 0; r < 4; ++r) {
        float s = lpart[r];
        s += __shfl_xor(s, 1);
        s += __shfl_xor(s, 2);
        s += __shfl_xor(s, 4);
        s += __shfl_xor(s, 8);
        lpart[r] = s;
    }

    if (!split) {
        if (l15 == 0) {
            #pragma unroll
            for (int r = 0; r < 4; ++r) lLds[w * 16 + q * 4 + r] = lpart[r];
        }
        __syncthreads();
        float linv[4];
        #pragma unroll
        for (int it = 0; it < 4; ++it) linv[it] = 1.f / lLds[it * 16 + l15];
        float* ob = outF + (size_t)b * CC * NN;
        #pragma unroll
        for (int ct = 0; ct < 8; ++ct)
            #pragma unroll
            for (int r = 0; r < 4; ++r) {
                int c = w * 128 + ct * 16 + q * 4 + r;
                float* orow = ob + (size_t)c * NN + i_base;
                #pragma unroll
                for (int it = 0; it < 4; ++it)
                    orow[it * 16 + l15] = o[ct][it][r] * linv[it];
            }
    } else {
        if (l15 == 0) {
            float* lg = (hf == 0) ? l0g : l1g;
            #pragma unroll
            for (int r = 0; r < 4; ++r)
                lg[(size_t)b * NN + i_base + w * 16 + q * 4 + r] = lpart[r];
        }
        if (hf == 0) {
            float* ob = outF + (size_t)b * CC * NN;
            #pragma unroll
            for (int ct = 0; ct < 8; ++ct)
                #pragma unroll
                for (int r = 0; r < 4; ++r) {
                    int c = w * 128 + ct * 16 + q * 4 + r;
                    float* orow = ob + (size_t)c * NN + i_base;
                    #pragma unroll
                    for (int it = 0; it < 4; ++it)
                        orow[it * 16 + l15] = o[ct][it][r];       // unnormalized
                }
        } else {
            u16* ob = outH + (size_t)b * CC * NN;
            #pragma unroll
            for (int ct = 0; ct < 8; ++ct)
                #pragma unroll
                for (int r = 0; r < 4; ++r) {
                    int c = w * 128 + ct * 16 + q * 4 + r;
                    u16* orow = ob + (size_t)c * NN + i_base;
                    #pragma unroll
                    for (int it = 0; it < 4; ++it)
                        orow[it * 16 + l15] = f2b(o[ct][it][r]);
                }
        }
    }
}

// combine: out = (O0 + O1) / (l0 + l1)   (same static M across splits)
__global__ __launch_bounds__(256) void combine_kernel(float* __restrict__ out,
                                                      const u16* __restrict__ P1,
                                                      const float* __restrict__ l0,
                                                      const float* __restrict__ l1) {
    size_t g = (size_t)blockIdx.x * 256 + threadIdx.x;
    size_t f = g * 4;
    int i = (int)(f & (NN - 1));
    int b = (int)(f >> 21);
    float4 p0 = *(float4*)&out[f];
    u64 pk = *(const u64*)&P1[f];
    float p0a[4] = {p0.x, p0.y, p0.z, p0.w};
    float r[4];
    #pragma unroll
    for (int k = 0; k < 4; ++k) {
        float l = l0[(size_t)b * NN + i + k] + l1[(size_t)b * NN + i + k];
        float p1f = b2f((u16)((pk >> (16 * k)) & 0xFFFFu));
        r[k] = (p0a[k] + p1f) / l;
    }
    *(float4*)&out[f] = (float4){r[0], r[1], r[2], r[3]};
}

extern "C" void kernel_launch(void* const* d_in, const int* in_sizes, int n_in,
                              void* d_out, int out_size, void* d_ws, size_t ws_size,
                              hipStream_t stream) {
    const float* x = (const float*)d_in[0];
    size_t SZ = (size_t)BB * NN * CC;          // elements
    u16* XT = (u16*)d_ws;
    u16* XN = XT + SZ;
    u16* P1 = XN + SZ;
    float* norms = (float*)(P1 + SZ);
    float* l0g   = norms + (size_t)BB * NN;
    float* l1g   = l0g + (size_t)BB * NN;
    int*   maxn  = (int*)(l1g + (size_t)BB * NN);
    size_t needed = 3 * SZ * 2 + 3 * (size_t)BB * NN * 4 + 64;
    int split = (ws_size >= needed) ? 1 : 0;
    float* out = (float*)d_out;
    if (!split) {
        norms = (float*)(XN + SZ);
        l0g = norms + (size_t)BB * NN;
        l1g = l0g;
        maxn = (int*)(l1g + (size_t)BB * NN);
    }

    hipMemsetAsync(maxn, 0, BB * sizeof(int), stream);
    prep_kernel<<<256, 256, 0, stream>>>(x, XT, XN, norms, maxn);
    if (split) {
        flash_kernel<<<512, 256, 0, stream>>>(XT, XN, norms, maxn, out, P1, l0g, l1g, 1);
        combine_kernel<<<(BB * CC * NN / 4) / 256, 256, 0, stream>>>(out, P1, l0g, l1g);
    } else {
        flash_kernel<<<256, 256, 0, stream>>>(XT, XN, norms, maxn, out, P1, l0g, l1g, 0);
    }
}

// Round 6
// 295.426 us; speedup vs baseline: 2.9149x; 1.2301x over previous
//
#include <hip/hip_runtime.h>
#include <hip/hip_bf16.h>

typedef unsigned short u16;
typedef unsigned int   u32;
typedef unsigned long long u64;
typedef __attribute__((ext_vector_type(8))) short bf16x8;  // 8 bf16 = 4 VGPRs
typedef __attribute__((ext_vector_type(4))) float f32x4;

#define BB 4
#define CC 512
#define NN 4096
#define LOG2E 1.44269504f

static __device__ __forceinline__ u16 f2b(float f) {
    __hip_bfloat16 h = __float2bfloat16(f);
    return *(u16*)&h;
}
static __device__ __forceinline__ u16 f2b_fast(float f) {   // round-half-up bf16
    u32 u = __builtin_bit_cast(u32, f);
    return (u16)((u + 0x8000u) >> 16);
}
static __device__ __forceinline__ float b2f(u16 b) {
    u32 u = (u32)b << 16;
    return __builtin_bit_cast(float, u);
}

// async global -> LDS, 16B per lane, wave-uniform LDS base + lane*16
typedef __attribute__((address_space(1))) const u32 GU32;
typedef __attribute__((address_space(3))) u32 LU32;
__device__ __forceinline__ void async16(const void* g, void* l) {
    __builtin_amdgcn_global_load_lds((GU32*)g, (LU32*)l, 16, 0, 0);
}

// ---------------------------------------------------------------------------
// prep: x fp32 [B][C][N] -> XT bf16 [B][N][C], XN bf16 [B][C][N],
//       norms[b][n] = sum_c x^2, maxn[b] = max_n norms (block owns all c)
// ---------------------------------------------------------------------------
__global__ __launch_bounds__(256) void prep_kernel(const float* __restrict__ x,
                                                   u16* __restrict__ XT,
                                                   u16* __restrict__ XN,
                                                   float* __restrict__ norms,
                                                   int* __restrict__ maxn) {
    __shared__ __align__(8) u16 tile[64][68];
    __shared__ float nsum[64];
    int blk = blockIdx.x;                  // 256 blocks
    int b  = blk >> 6;
    int n0 = (blk & 63) << 6;
    int t  = threadIdx.x;
    if (t < 64) nsum[t] = 0.f;

    int nq    = t & 15;
    int rbase = t >> 4;
    float psum[4] = {0.f, 0.f, 0.f, 0.f};

    for (int c0 = 0; c0 < CC; c0 += 64) {
        #pragma unroll
        for (int p = 0; p < 4; ++p) {
            int cl = p * 16 + rbase;
            const float* src = x + ((size_t)(b * CC + c0 + cl) * NN) + n0 + nq * 4;
            float4 v = *(const float4*)src;
            psum[0] += v.x * v.x; psum[1] += v.y * v.y;
            psum[2] += v.z * v.z; psum[3] += v.w * v.w;
            u64 pk = (u64)f2b(v.x) | ((u64)f2b(v.y) << 16) |
                     ((u64)f2b(v.z) << 32) | ((u64)f2b(v.w) << 48);
            *(u64*)&XN[((size_t)(b * CC + c0 + cl) * NN) + n0 + nq * 4] = pk;
            *(u64*)&tile[cl][nq * 4] = pk;
        }
        __syncthreads();
        int c2 = (t & 31) * 2;             // 0..62 even
        int nb = t >> 5;                   // 0..7
        #pragma unroll
        for (int rr = 0; rr < 8; ++rr) {
            int nl = rr * 8 + nb;
            u32 val = (u32)tile[c2][nl] | ((u32)tile[c2 + 1][nl] << 16);
            *(u32*)&XT[((size_t)(b * NN + n0 + nl) * CC) + c0 + c2] = val;
        }
        __syncthreads();
    }
    #pragma unroll
    for (int k = 0; k < 4; ++k) atomicAdd(&nsum[nq * 4 + k], psum[k]);
    __syncthreads();
    if (t < 64) {
        float v = nsum[t];
        norms[(size_t)b * NN + n0 + t] = v;
        float m = v;
        #pragma unroll
        for (int d = 1; d < 64; d <<= 1) m = fmaxf(m, __shfl_xor(m, d));
        if (t == 0) atomicMax(&maxn[b], __float_as_int(m));  // norms >= 0
    }
}

// ---------------------------------------------------------------------------
// flash attention, static per-row max bound. EXACT R3 loop body (210 us
// proven): per-iteration j0-relative addresses. Do NOT hoist pointers across
// iterations (R5: -34%) and do NOT add live loop state (R4: spills at the
// 256 reg/wave cliff: o=128 AGPR + qf 64 + vf 32 + s 8 + addr).
// ---------------------------------------------------------------------------
__global__ __launch_bounds__(256, 2) void flash_kernel(const u16* __restrict__ XT,
                                                       const u16* __restrict__ XN,
                                                       const float* __restrict__ norms,
                                                       const int* __restrict__ maxn,
                                                       float* __restrict__ outF,
                                                       u16* __restrict__ outH,
                                                       float* __restrict__ l0g,
                                                       float* __restrict__ l1g,
                                                       int split) {
    __shared__ __align__(16) u16 KtT[2][32 * 520];        // [j][c], stride 520
    __shared__ __align__(16) u16 Plds[2][64 * 40];
    __shared__ float lLds[64];

    int blk   = blockIdx.x;
    int inner = blk & 255;
    int hf    = split ? (blk >> 8) : 0;
    int xcd = inner & 7;
    int b   = xcd >> 1;
    int ib  = (inner >> 3) + ((xcd & 1) << 5);
    int i_base = ib * 64;
    int jlo = hf * (NN / 2) * split;
    int njt = split ? 64 : 128;

    int t    = threadIdx.x;
    int w    = t >> 6;
    int lane = t & 63;
    int l15  = lane & 15;
    int q    = lane >> 4;

    const u16* xtb = XT + (size_t)b * NN * CC;
    const u16* xnb = XN + (size_t)b * CC * NN;

    float mxn = __int_as_float(maxn[b]);
    float M2[4];
    #pragma unroll
    for (int r = 0; r < 4; ++r) {
        float nr = norms[(size_t)b * NN + i_base + w * 16 + q * 4 + r];
        M2[r] = (sqrtf(nr * mxn) - 40.f) * LOG2E;
    }

    // Q fragments: rows i_base + w*16 + l15, all 512 c
    bf16x8 qf[16];
    {
        const u16* qrow = xtb + (size_t)(i_base + w * 16 + l15) * CC;
        #pragma unroll
        for (int kk = 0; kk < 16; ++kk)
            qf[kk] = *(const bf16x8*)(qrow + kk * 32 + q * 8);
    }

    f32x4 o[8][4];
    #pragma unroll
    for (int ct = 0; ct < 8; ++ct)
        #pragma unroll
        for (int it = 0; it < 4; ++it)
            o[ct][it] = (f32x4){0.f, 0.f, 0.f, 0.f};
    float lpart[4] = {0.f, 0.f, 0.f, 0.f};

    // prologue: stage tile 0
    {
        const u16* src = xtb + (size_t)(jlo + w * 8) * CC + lane * 8;
        #pragma unroll
        for (int rr = 0; rr < 8; ++rr)
            async16(src + rr * CC, &KtT[0][(w * 8 + rr) * 520]);
    }
    __syncthreads();

    for (int jt = 0; jt < njt; ++jt) {
        int buf = jt & 1;
        int j0  = jlo + jt * 32;

        // V fragments for THIS iter (drained at the barrier below)
        bf16x8 vf[8];
        #pragma unroll
        for (int ct = 0; ct < 8; ++ct)
            vf[ct] = *(const bf16x8*)(xnb + (size_t)(w * 128 + ct * 16 + l15) * NN + j0 + q * 8);

        // stage NEXT K-tile into the other buffer
        if (jt + 1 < njt) {
            const u16* src = xtb + (size_t)(j0 + 32 + w * 8) * CC + lane * 8;
            #pragma unroll
            for (int rr = 0; rr < 8; ++rr)
                async16(src + rr * CC, &KtT[buf ^ 1][(w * 8 + rr) * 520]);
        }

        // GEMM1: S[16 rows][32 j] from KtT[buf]  (2 chains — do not widen)
        f32x4 s0 = {0.f,0.f,0.f,0.f}, s1 = {0.f,0.f,0.f,0.f};
        #pragma unroll
        for (int kk = 0; kk < 16; ++kk) {
            bf16x8 b0 = *(const bf16x8*)&KtT[buf][(l15)      * 520 + kk * 32 + q * 8];
            bf16x8 b1 = *(const bf16x8*)&KtT[buf][(16 + l15) * 520 + kk * 32 + q * 8];
            s0 = __builtin_amdgcn_mfma_f32_16x16x32_bf16(qf[kk], b0, s0, 0, 0, 0);
            s1 = __builtin_amdgcn_mfma_f32_16x16x32_bf16(qf[kk], b1, s1, 0, 0, 0);
        }

        // softmax-lite: p = 2^(s*log2e - M2); no shuffles, no rescale
        #pragma unroll
        for (int r = 0; r < 4; ++r) {
            float p0 = __builtin_amdgcn_exp2f(fmaf(s0[r], LOG2E, -M2[r]));
            float p1 = __builtin_amdgcn_exp2f(fmaf(s1[r], LOG2E, -M2[r]));
            u16 h0 = f2b_fast(p0), h1 = f2b_fast(p1);
            lpart[r] += b2f(h0) + b2f(h1);       // l consistent with bf16 P
            int row = w * 16 + q * 4 + r;
            Plds[buf][row * 40 +      l15] = h0;
            Plds[buf][row * 40 + 16 + l15] = h1;
        }
        __syncthreads();   // drains vf + stage(i+1); P ready

        // GEMM2: O^T += V P^T
        bf16x8 pb[4];
        #pragma unroll
        for (int it = 0; it < 4; ++it)
            pb[it] = *(const bf16x8*)&Plds[buf][(it * 16 + l15) * 40 + q * 8];
        #pragma unroll
        for (int ct = 0; ct < 8; ++ct)
            #pragma unroll
            for (int it = 0; it < 4; ++it)
                o[ct][it] = __builtin_amdgcn_mfma_f32_16x16x32_bf16(vf[ct], pb[it], o[ct][it], 0, 0, 0);
    }

    // reduce l over the 16 column-lanes (once)
    #pragma unroll
    for (int r = 0; r < 4; ++r) {
        float s = lpart[r];
        s += __shfl_xor(s, 1);
        s += __shfl_xor(s, 2);
        s += __shfl_xor(s, 4);
        s += __shfl_xor(s, 8);
        lpart[r] = s;
    }

    if (!split) {
        if (l15 == 0) {
            #pragma unroll
            for (int r = 0; r < 4; ++r) lLds[w * 16 + q * 4 + r] = lpart[r];
        }
        __syncthreads();
        float linv[4];
        #pragma unroll
        for (int it = 0; it < 4; ++it) linv[it] = 1.f / lLds[it * 16 + l15];
        float* ob = outF + (size_t)b * CC * NN;
        #pragma unroll
        for (int ct = 0; ct < 8; ++ct)
            #pragma unroll
            for (int r = 0; r < 4; ++r) {
                int c = w * 128 + ct * 16 + q * 4 + r;
                float* orow = ob + (size_t)c * NN + i_base;
                #pragma unroll
                for (int it = 0; it < 4; ++it)
                    orow[it * 16 + l15] = o[ct][it][r] * linv[it];
            }
    } else {
        if (l15 == 0) {
            float* lg = (hf == 0) ? l0g : l1g;
            #pragma unroll
            for (int r = 0; r < 4; ++r)
                lg[(size_t)b * NN + i_base + w * 16 + q * 4 + r] = lpart[r];
        }
        if (hf == 0) {
            float* ob = outF + (size_t)b * CC * NN;
            #pragma unroll
            for (int ct = 0; ct < 8; ++ct)
                #pragma unroll
                for (int r = 0; r < 4; ++r) {
                    int c = w * 128 + ct * 16 + q * 4 + r;
                    float* orow = ob + (size_t)c * NN + i_base;
                    #pragma unroll
                    for (int it = 0; it < 4; ++it)
                        orow[it * 16 + l15] = o[ct][it][r];       // unnormalized
                }
        } else {
            u16* ob = outH + (size_t)b * CC * NN;
            #pragma unroll
            for (int ct = 0; ct < 8; ++ct)
                #pragma unroll
                for (int r = 0; r < 4; ++r) {
                    int c = w * 128 + ct * 16 + q * 4 + r;
                    u16* orow = ob + (size_t)c * NN + i_base;
                    #pragma unroll
                    for (int it = 0; it < 4; ++it)
                        orow[it * 16 + l15] = f2b(o[ct][it][r]);
                }
        }
    }
}

// combine: out = (O0 + O1) / (l0 + l1)   (same static M across splits)
__global__ __launch_bounds__(256) void combine_kernel(float* __restrict__ out,
                                                      const u16* __restrict__ P1,
                                                      const float* __restrict__ l0,
                                                      const float* __restrict__ l1) {
    size_t g = (size_t)blockIdx.x * 256 + threadIdx.x;
    size_t f = g * 4;
    int i = (int)(f & (NN - 1));
    int b = (int)(f >> 21);
    float4 p0 = *(float4*)&out[f];
    u64 pk = *(const u64*)&P1[f];
    float p0a[4] = {p0.x, p0.y, p0.z, p0.w};
    float r[4];
    #pragma unroll
    for (int k = 0; k < 4; ++k) {
        float l = l0[(size_t)b * NN + i + k] + l1[(size_t)b * NN + i + k];
        float p1f = b2f((u16)((pk >> (16 * k)) & 0xFFFFu));
        r[k] = (p0a[k] + p1f) / l;
    }
    *(float4*)&out[f] = (float4){r[0], r[1], r[2], r[3]};
}

extern "C" void kernel_launch(void* const* d_in, const int* in_sizes, int n_in,
                              void* d_out, int out_size, void* d_ws, size_t ws_size,
                              hipStream_t stream) {
    const float* x = (const float*)d_in[0];
    size_t SZ = (size_t)BB * NN * CC;          // elements
    u16* XT = (u16*)d_ws;
    u16* XN = XT + SZ;
    u16* P1 = XN + SZ;
    float* norms = (float*)(P1 + SZ);
    float* l0g   = norms + (size_t)BB * NN;
    float* l1g   = l0g + (size_t)BB * NN;
    int*   maxn  = (int*)(l1g + (size_t)BB * NN);
    size_t needed = 3 * SZ * 2 + 3 * (size_t)BB * NN * 4 + 64;
    int split = (ws_size >= needed) ? 1 : 0;
    float* out = (float*)d_out;
    if (!split) {
        norms = (float*)(XN + SZ);
        l0g = norms + (size_t)BB * NN;
        l1g = l0g;
        maxn = (int*)(l1g + (size_t)BB * NN);
    }

    hipMemsetAsync(maxn, 0, BB * sizeof(int), stream);
    prep_kernel<<<256, 256, 0, stream>>>(x, XT, XN, norms, maxn);
    if (split) {
        flash_kernel<<<512, 256, 0, stream>>>(XT, XN, norms, maxn, out, P1, l0g, l1g, 1);
        combine_kernel<<<(BB * CC * NN / 4) / 256, 256, 0, stream>>>(out, P1, l0g, l1g);
    } else {
        flash_kernel<<<256, 256, 0, stream>>>(XT, XN, norms, maxn, out, P1, l0g, l1g, 0);
    }
}

// Round 7
// 294.083 us; speedup vs baseline: 2.9283x; 1.0046x over previous
//
#include <hip/hip_runtime.h>
#include <hip/hip_bf16.h>

typedef unsigned short u16;
typedef unsigned int   u32;
typedef unsigned long long u64;
typedef __attribute__((ext_vector_type(8))) short bf16x8;  // 8 bf16 = 4 VGPRs
typedef __attribute__((ext_vector_type(4))) float f32x4;

#define BB 4
#define CC 512
#define NN 4096
#define LOG2E 1.44269504f

static __device__ __forceinline__ u16 f2b(float f) {
    __hip_bfloat16 h = __float2bfloat16(f);
    return *(u16*)&h;
}
static __device__ __forceinline__ u16 f2b_fast(float f) {   // round-half-up bf16
    u32 u = __builtin_bit_cast(u32, f);
    return (u16)((u + 0x8000u) >> 16);
}
static __device__ __forceinline__ float b2f(u16 b) {
    u32 u = (u32)b << 16;
    return __builtin_bit_cast(float, u);
}

// async global -> LDS, 16B per lane, wave-uniform LDS base + lane*16
typedef __attribute__((address_space(1))) const u32 GU32;
typedef __attribute__((address_space(3))) u32 LU32;
__device__ __forceinline__ void async16(const void* g, void* l) {
    __builtin_amdgcn_global_load_lds((GU32*)g, (LU32*)l, 16, 0, 0);
}

// ---------------------------------------------------------------------------
// prep: 2048 blocks, each 64c x 64n tile of one batch.
//   x fp32 [B][C][N] -> XT bf16 [B][N][C], XN bf16 [B][C][N],
//   normp[cg][b][n] = partial sum_c x^2 over this block's 64 c (NO atomics)
// ---------------------------------------------------------------------------
__global__ __launch_bounds__(256) void prep_kernel(const float* __restrict__ x,
                                                   u16* __restrict__ XT,
                                                   u16* __restrict__ XN,
                                                   float* __restrict__ normp) {
    __shared__ __align__(8) u16 tile[64][68];
    __shared__ float nsum[64];
    int blk = blockIdx.x;                  // 2048 blocks
    int b  = blk >> 9;
    int r2 = blk & 511;
    int cg = r2 >> 6;                      // c-group 0..7
    int c0 = cg << 6;
    int n0 = (r2 & 63) << 6;
    int t  = threadIdx.x;
    if (t < 64) nsum[t] = 0.f;

    int nq    = t & 15;                    // float4 index along n
    int rbase = t >> 4;                    // 0..15
    float psum[4] = {0.f, 0.f, 0.f, 0.f};
    #pragma unroll
    for (int p = 0; p < 4; ++p) {
        int cl = p * 16 + rbase;           // 0..63
        const float* src = x + ((size_t)(b * CC + c0 + cl) * NN) + n0 + nq * 4;
        float4 v = *(const float4*)src;
        psum[0] += v.x * v.x; psum[1] += v.y * v.y;
        psum[2] += v.z * v.z; psum[3] += v.w * v.w;
        u64 pk = (u64)f2b(v.x) | ((u64)f2b(v.y) << 16) |
                 ((u64)f2b(v.z) << 32) | ((u64)f2b(v.w) << 48);
        *(u64*)&XN[((size_t)(b * CC + c0 + cl) * NN) + n0 + nq * 4] = pk;
        *(u64*)&tile[cl][nq * 4] = pk;
    }
    __syncthreads();                       // tile complete; nsum init visible

    // XT writes: 4 c per thread, u64 stores
    {
        int c4 = (t & 15) * 4;             // 0,4,..,60
        int nb = t >> 4;                   // 0..15
        #pragma unroll
        for (int rr = 0; rr < 4; ++rr) {
            int nl = rr * 16 + nb;
            u64 pk = (u64)tile[c4][nl] | ((u64)tile[c4 + 1][nl] << 16) |
                     ((u64)tile[c4 + 2][nl] << 32) | ((u64)tile[c4 + 3][nl] << 48);
            *(u64*)&XT[((size_t)(b * NN + n0 + nl) * CC) + c0 + c4] = pk;
        }
    }
    // norm partials via LDS atomics (block-local), then one plain store
    #pragma unroll
    for (int k = 0; k < 4; ++k) atomicAdd(&nsum[nq * 4 + k], psum[k]);
    __syncthreads();
    if (t < 64)
        normp[((size_t)cg * BB + b) * NN + n0 + t] = nsum[t];
}

// ---------------------------------------------------------------------------
// nred: norms[b][n] = sum_cg normp[cg][b][n]; maxn[b] = max_n norms.
// 4 blocks (one per batch) x 1024 threads; no atomics, no memset needed.
// ---------------------------------------------------------------------------
__global__ __launch_bounds__(1024) void nred_kernel(const float* __restrict__ normp,
                                                    float* __restrict__ norms,
                                                    int* __restrict__ maxn) {
    int b = blockIdx.x;
    int t = threadIdx.x;
    float m = 0.f;
    #pragma unroll
    for (int k = 0; k < 4; ++k) {
        int n = k * 1024 + t;
        float s = 0.f;
        #pragma unroll
        for (int cg = 0; cg < 8; ++cg)
            s += normp[((size_t)cg * BB + b) * NN + n];
        norms[(size_t)b * NN + n] = s;
        m = fmaxf(m, s);
    }
    #pragma unroll
    for (int d = 1; d < 64; d <<= 1) m = fmaxf(m, __shfl_xor(m, d));
    __shared__ float wred[16];
    if ((t & 63) == 0) wred[t >> 6] = m;
    __syncthreads();
    if (t < 16) {
        float v = wred[t];
        #pragma unroll
        for (int d = 1; d < 16; d <<= 1) v = fmaxf(v, __shfl_xor(v, d));
        if (t == 0) maxn[b] = __float_as_int(v);
    }
}

// ---------------------------------------------------------------------------
// flash attention, static per-row max bound. EXACT R3/R6 loop body (210 us
// proven): per-iteration j0-relative addresses. Do NOT hoist pointers across
// iterations (R5: -34%) and do NOT add live loop state (R4: spills at the
// 256 reg/wave cliff: o=128 AGPR + qf 64 + vf 32 + s 8 + addr).
// ---------------------------------------------------------------------------
__global__ __launch_bounds__(256, 2) void flash_kernel(const u16* __restrict__ XT,
                                                       const u16* __restrict__ XN,
                                                       const float* __restrict__ norms,
                                                       const int* __restrict__ maxn,
                                                       float* __restrict__ outF,
                                                       u16* __restrict__ outH,
                                                       float* __restrict__ l0g,
                                                       float* __restrict__ l1g,
                                                       int split) {
    __shared__ __align__(16) u16 KtT[2][32 * 520];        // [j][c], stride 520
    __shared__ __align__(16) u16 Plds[2][64 * 40];
    __shared__ float lLds[64];

    int blk   = blockIdx.x;
    int inner = blk & 255;
    int hf    = split ? (blk >> 8) : 0;
    int xcd = inner & 7;
    int b   = xcd >> 1;
    int ib  = (inner >> 3) + ((xcd & 1) << 5);
    int i_base = ib * 64;
    int jlo = hf * (NN / 2) * split;
    int njt = split ? 64 : 128;

    int t    = threadIdx.x;
    int w    = t >> 6;
    int lane = t & 63;
    int l15  = lane & 15;
    int q    = lane >> 4;

    const u16* xtb = XT + (size_t)b * NN * CC;
    const u16* xnb = XN + (size_t)b * CC * NN;

    float mxn = __int_as_float(maxn[b]);
    float M2[4];
    #pragma unroll
    for (int r = 0; r < 4; ++r) {
        float nr = norms[(size_t)b * NN + i_base + w * 16 + q * 4 + r];
        M2[r] = (sqrtf(nr * mxn) - 40.f) * LOG2E;
    }

    // Q fragments: rows i_base + w*16 + l15, all 512 c
    bf16x8 qf[16];
    {
        const u16* qrow = xtb + (size_t)(i_base + w * 16 + l15) * CC;
        #pragma unroll
        for (int kk = 0; kk < 16; ++kk)
            qf[kk] = *(const bf16x8*)(qrow + kk * 32 + q * 8);
    }

    f32x4 o[8][4];
    #pragma unroll
    for (int ct = 0; ct < 8; ++ct)
        #pragma unroll
        for (int it = 0; it < 4; ++it)
            o[ct][it] = (f32x4){0.f, 0.f, 0.f, 0.f};
    float lpart[4] = {0.f, 0.f, 0.f, 0.f};

    // prologue: stage tile 0
    {
        const u16* src = xtb + (size_t)(jlo + w * 8) * CC + lane * 8;
        #pragma unroll
        for (int rr = 0; rr < 8; ++rr)
            async16(src + rr * CC, &KtT[0][(w * 8 + rr) * 520]);
    }
    __syncthreads();

    for (int jt = 0; jt < njt; ++jt) {
        int buf = jt & 1;
        int j0  = jlo + jt * 32;

        // V fragments for THIS iter (drained at the barrier below)
        bf16x8 vf[8];
        #pragma unroll
        for (int ct = 0; ct < 8; ++ct)
            vf[ct] = *(const bf16x8*)(xnb + (size_t)(w * 128 + ct * 16 + l15) * NN + j0 + q * 8);

        // stage NEXT K-tile into the other buffer
        if (jt + 1 < njt) {
            const u16* src = xtb + (size_t)(j0 + 32 + w * 8) * CC + lane * 8;
            #pragma unroll
            for (int rr = 0; rr < 8; ++rr)
                async16(src + rr * CC, &KtT[buf ^ 1][(w * 8 + rr) * 520]);
        }

        // GEMM1: S[16 rows][32 j] from KtT[buf]  (2 chains — do not widen)
        f32x4 s0 = {0.f,0.f,0.f,0.f}, s1 = {0.f,0.f,0.f,0.f};
        #pragma unroll
        for (int kk = 0; kk < 16; ++kk) {
            bf16x8 b0 = *(const bf16x8*)&KtT[buf][(l15)      * 520 + kk * 32 + q * 8];
            bf16x8 b1 = *(const bf16x8*)&KtT[buf][(16 + l15) * 520 + kk * 32 + q * 8];
            s0 = __builtin_amdgcn_mfma_f32_16x16x32_bf16(qf[kk], b0, s0, 0, 0, 0);
            s1 = __builtin_amdgcn_mfma_f32_16x16x32_bf16(qf[kk], b1, s1, 0, 0, 0);
        }

        // softmax-lite: p = 2^(s*log2e - M2); no shuffles, no rescale
        #pragma unroll
        for (int r = 0; r < 4; ++r) {
            float p0 = __builtin_amdgcn_exp2f(fmaf(s0[r], LOG2E, -M2[r]));
            float p1 = __builtin_amdgcn_exp2f(fmaf(s1[r], LOG2E, -M2[r]));
            u16 h0 = f2b_fast(p0), h1 = f2b_fast(p1);
            lpart[r] += b2f(h0) + b2f(h1);       // l consistent with bf16 P
            int row = w * 16 + q * 4 + r;
            Plds[buf][row * 40 +      l15] = h0;
            Plds[buf][row * 40 + 16 + l15] = h1;
        }
        __syncthreads();   // drains vf + stage(i+1); P ready

        // GEMM2: O^T += V P^T
        bf16x8 pb[4];
        #pragma unroll
        for (int it = 0; it < 4; ++it)
            pb[it] = *(const bf16x8*)&Plds[buf][(it * 16 + l15) * 40 + q * 8];
        #pragma unroll
        for (int ct = 0; ct < 8; ++ct)
            #pragma unroll
            for (int it = 0; it < 4; ++it)
                o[ct][it] = __builtin_amdgcn_mfma_f32_16x16x32_bf16(vf[ct], pb[it], o[ct][it], 0, 0, 0);
    }

    // reduce l over the 16 column-lanes (once)
    #pragma unroll
    for (int r = 0; r < 4; ++r) {
        float s = lpart[r];
        s += __shfl_xor(s, 1);
        s += __shfl_xor(s, 2);
        s += __shfl_xor(s, 4);
        s += __shfl_xor(s, 8);
        lpart[r] = s;
    }

    if (!split) {
        if (l15 == 0) {
            #pragma unroll
            for (int r = 0; r < 4; ++r) lLds[w * 16 + q * 4 + r] = lpart[r];
        }
        __syncthreads();
        float linv[4];
        #pragma unroll
        for (int it = 0; it < 4; ++it) linv[it] = 1.f / lLds[it * 16 + l15];
        float* ob = outF + (size_t)b * CC * NN;
        #pragma unroll
        for (int ct = 0; ct < 8; ++ct)
            #pragma unroll
            for (int r = 0; r < 4; ++r) {
                int c = w * 128 + ct * 16 + q * 4 + r;
                float* orow = ob + (size_t)c * NN + i_base;
                #pragma unroll
                for (int it = 0; it < 4; ++it)
                    orow[it * 16 + l15] = o[ct][it][r] * linv[it];
            }
    } else {
        if (l15 == 0) {
            float* lg = (hf == 0) ? l0g : l1g;
            #pragma unroll
            for (int r = 0; r < 4; ++r)
                lg[(size_t)b * NN + i_base + w * 16 + q * 4 + r] = lpart[r];
        }
        if (hf == 0) {
            float* ob = outF + (size_t)b * CC * NN;
            #pragma unroll
            for (int ct = 0; ct < 8; ++ct)
                #pragma unroll
                for (int r = 0; r < 4; ++r) {
                    int c = w * 128 + ct * 16 + q * 4 + r;
                    float* orow = ob + (size_t)c * NN + i_base;
                    #pragma unroll
                    for (int it = 0; it < 4; ++it)
                        orow[it * 16 + l15] = o[ct][it][r];       // unnormalized
                }
        } else {
            u16* ob = outH + (size_t)b * CC * NN;
            #pragma unroll
            for (int ct = 0; ct < 8; ++ct)
                #pragma unroll
                for (int r = 0; r < 4; ++r) {
                    int c = w * 128 + ct * 16 + q * 4 + r;
                    u16* orow = ob + (size_t)c * NN + i_base;
                    #pragma unroll
                    for (int it = 0; it < 4; ++it)
                        orow[it * 16 + l15] = f2b(o[ct][it][r]);
                }
        }
    }
}

// combine: out = (O0 + O1) / (l0 + l1)   (same static M across splits)
__global__ __launch_bounds__(256) void combine_kernel(float* __restrict__ out,
                                                      const u16* __restrict__ P1,
                                                      const float* __restrict__ l0,
                                                      const float* __restrict__ l1) {
    size_t g = (size_t)blockIdx.x * 256 + threadIdx.x;
    size_t f = g * 4;
    int i = (int)(f & (NN - 1));
    int b = (int)(f >> 21);
    float4 p0 = *(float4*)&out[f];
    u64 pk = *(const u64*)&P1[f];
    float p0a[4] = {p0.x, p0.y, p0.z, p0.w};
    float r[4];
    #pragma unroll
    for (int k = 0; k < 4; ++k) {
        float l = l0[(size_t)b * NN + i + k] + l1[(size_t)b * NN + i + k];
        float p1f = b2f((u16)((pk >> (16 * k)) & 0xFFFFu));
        r[k] = (p0a[k] + p1f) / l;
    }
    *(float4*)&out[f] = (float4){r[0], r[1], r[2], r[3]};
}

extern "C" void kernel_launch(void* const* d_in, const int* in_sizes, int n_in,
                              void* d_out, int out_size, void* d_ws, size_t ws_size,
                              hipStream_t stream) {
    const float* x = (const float*)d_in[0];
    size_t SZ = (size_t)BB * NN * CC;          // elements
    size_t BN = (size_t)BB * NN;
    u16* XT = (u16*)d_ws;
    u16* XN = XT + SZ;
    u16* P1 = XN + SZ;
    float* norms = (float*)(P1 + SZ);
    float* l0g   = norms + BN;
    float* l1g   = l0g + BN;
    float* normp = l1g + BN;                   // 8 * B * N floats
    int*   maxn  = (int*)(normp + 8 * BN);
    size_t needed = 3 * SZ * 2 + 3 * BN * 4 + 8 * BN * 4 + 64;
    int split = (ws_size >= needed) ? 1 : 0;
    float* out = (float*)d_out;
    if (!split) {   // fallback layout without P1
        norms = (float*)(XN + SZ);
        l0g = norms + BN;
        l1g = l0g;
        normp = l1g + BN;
        maxn = (int*)(normp + 8 * BN);
    }

    prep_kernel<<<2048, 256, 0, stream>>>(x, XT, XN, normp);
    nred_kernel<<<BB, 1024, 0, stream>>>(normp, norms, maxn);
    if (split) {
        flash_kernel<<<512, 256, 0, stream>>>(XT, XN, norms, maxn, out, P1, l0g, l1g, 1);
        combine_kernel<<<(BB * CC * NN / 4) / 256, 256, 0, stream>>>(out, P1, l0g, l1g);
    } else {
        flash_kernel<<<256, 256, 0, stream>>>(XT, XN, norms, maxn, out, P1, l0g, l1g, 0);
    }
}